// Round 10
// baseline (214.175 us; speedup 1.0000x reference)
//
#include <hip/hip_runtime.h>

#define N_NODES 100000
#define N_EDGES 1200000
#define D_IN 256
#define D_OUT 64

#define BUCKET_BITS 5
#define BUCKET_ROWS 32
#define N_BUCKETS   (N_NODES / BUCKET_ROWS)      // 3125 exact
#define NBLK_E      640
#define EPB         (N_EDGES / NBLK_E)           // 1875 exact
#define C2D_STRIDE  3136                          // padded row (64B aligned)
#define CPL         10                            // chunks per lane (640/64)

// ---- workspace layout (bytes) ----------------------------------------------
// c2d is chunk-major [NBLK_E][C2D_STRIDE] and ALIASES the edge_s region:
// it is fully consumed by bucket_scatter2 before bucket_sort writes edge_s.
#define OFF_SUPPORT   0u            // bf16 support: 12,800,000
#define OFF_ROWSTART  12800000u     // (N_NODES+1)*4 -> pad 400,016
#define OFF_COUNTS    13200016u     // 400,000
#define OFF_ETMP      13600016u     // 1.2M*8 = 9,600,000
#define OFF_EDGES     23200016u     // 9,600,000  (c2d alias: 640*3136*4 = 8,028,160)
#define OFF_C2D       OFF_EDGES
#define OFF_BLKSUMS   32800016u     // 2,048
#define WS_NEEDED     32802064u

using bf16x8 = __attribute__((ext_vector_type(8))) short;
using f32x4  = __attribute__((ext_vector_type(4))) float;

static __device__ __forceinline__ ushort f32_to_bf16_rne(float f) {
    unsigned bits = __float_as_uint(f);
    unsigned r = (bits + 0x7FFFu + ((bits >> 16) & 1u)) >> 16;
    return (ushort)r;
}
static __device__ __forceinline__ float bf16_to_f32(ushort u) {
    return __uint_as_float((unsigned)u << 16);
}
static __device__ __forceinline__ unsigned pack2bf(float a, float b) {
    return (unsigned)f32_to_bf16_rne(a) | ((unsigned)f32_to_bf16_rne(b) << 16);
}

// ---------------------------------------------------------------------------
// support(bf16) = X @ W — MFMA 16x16x32 bf16 (unchanged, verified R4-R8).
// ---------------------------------------------------------------------------
__global__ __launch_bounds__(256, 4) void gemm_xw_mfma(const float* __restrict__ X,
                                                       const float* __restrict__ W,
                                                       ushort* __restrict__ support) {
    __shared__ ushort XsT[4][128][8];
    __shared__ ushort WtT[32][64][8];

    const int t = threadIdx.x;
    const int row0 = blockIdx.x * 128;
    const int lane = t & 63;
    const int w = t >> 6;
    const int lr = lane & 15;
    const int lg = lane >> 4;

#pragma unroll
    for (int p = 0; p < 16; ++p) {
        int idx = t + p * 256;
        int k   = idx >> 4;
        int c4  = idx & 15;
        float4 v = *reinterpret_cast<const float4*>(W + (size_t)k * D_OUT + c4 * 4);
        WtT[k >> 3][c4 * 4 + 0][k & 7] = f32_to_bf16_rne(v.x);
        WtT[k >> 3][c4 * 4 + 1][k & 7] = f32_to_bf16_rne(v.y);
        WtT[k >> 3][c4 * 4 + 2][k & 7] = f32_to_bf16_rne(v.z);
        WtT[k >> 3][c4 * 4 + 3][k & 7] = f32_to_bf16_rne(v.w);
    }

    int  xrow[4], xq[4];
    bool xval[4];
#pragma unroll
    for (int p = 0; p < 4; ++p) {
        int idx = t + p * 256;
        xrow[p] = idx >> 3;
        xq[p]   = idx & 7;
        xval[p] = (row0 + xrow[p]) < N_NODES;
    }

    float4 xreg[4];
#pragma unroll
    for (int p = 0; p < 4; ++p) {
        xreg[p] = make_float4(0.f, 0.f, 0.f, 0.f);
        if (xval[p])
            xreg[p] = *reinterpret_cast<const float4*>(
                X + (size_t)(row0 + xrow[p]) * D_IN + xq[p] * 4);
    }

    f32x4 acc[2][4];
#pragma unroll
    for (int mi = 0; mi < 2; ++mi)
#pragma unroll
        for (int ni = 0; ni < 4; ++ni) acc[mi][ni] = (f32x4){0.f, 0.f, 0.f, 0.f};

    for (int kt = 0; kt < 8; ++kt) {
#pragma unroll
        for (int p = 0; p < 4; ++p) {
            uint2 u;
            u.x = pack2bf(xreg[p].x, xreg[p].y);
            u.y = pack2bf(xreg[p].z, xreg[p].w);
            *reinterpret_cast<uint2*>(&XsT[xq[p] >> 1][xrow[p]][(xq[p] & 1) * 4]) = u;
        }
        __syncthreads();

        if (kt < 7) {
#pragma unroll
            for (int p = 0; p < 4; ++p) {
                if (xval[p])
                    xreg[p] = *reinterpret_cast<const float4*>(
                        X + (size_t)(row0 + xrow[p]) * D_IN + (kt + 1) * 32 + xq[p] * 4);
            }
        }

        bf16x8 a0 = *reinterpret_cast<const bf16x8*>(&XsT[lg][w * 32 + lr][0]);
        bf16x8 a1 = *reinterpret_cast<const bf16x8*>(&XsT[lg][w * 32 + 16 + lr][0]);
#pragma unroll
        for (int ni = 0; ni < 4; ++ni) {
            bf16x8 b = *reinterpret_cast<const bf16x8*>(&WtT[kt * 4 + lg][ni * 16 + lr][0]);
            acc[0][ni] = __builtin_amdgcn_mfma_f32_16x16x32_bf16(a0, b, acc[0][ni], 0, 0, 0);
            acc[1][ni] = __builtin_amdgcn_mfma_f32_16x16x32_bf16(a1, b, acc[1][ni], 0, 0, 0);
        }
        __syncthreads();
    }

#pragma unroll
    for (int mi = 0; mi < 2; ++mi) {
#pragma unroll
        for (int reg = 0; reg < 4; ++reg) {
            int grow = row0 + w * 32 + mi * 16 + lg * 4 + reg;
            if (grow < N_NODES) {
#pragma unroll
                for (int ni = 0; ni < 4; ++ni)
                    support[(size_t)grow * D_OUT + ni * 16 + lr] =
                        f32_to_bf16_rne(acc[mi][ni][reg]);
            }
        }
    }
}

// ---------------------------------------------------------------------------
// CSR build: per-row counts + scan (validated R2-R8, cheap).
// ---------------------------------------------------------------------------
__global__ void zero_ints(int* __restrict__ a, int n) {
    int i = blockIdx.x * blockDim.x + threadIdx.x;
    int stride = gridDim.x * blockDim.x;
    for (; i < n; i += stride) a[i] = 0;
}

__global__ void hist_rows(const int* __restrict__ rows, int* __restrict__ counts) {
    int i = blockIdx.x * blockDim.x + threadIdx.x;
    int stride = gridDim.x * blockDim.x;
    for (; i < N_EDGES; i += stride) atomicAdd(&counts[rows[i]], 1);
}

__global__ __launch_bounds__(256) void scan_l1(const int* __restrict__ counts,
                                               int* __restrict__ row_start,
                                               int* __restrict__ blkSums) {
    __shared__ int s[256];
    const int t = threadIdx.x;
    const int i = blockIdx.x * 256 + t;
    int v = (i < N_NODES) ? counts[i] : 0;
    s[t] = v;
    __syncthreads();
#pragma unroll
    for (int off = 1; off < 256; off <<= 1) {
        int x = (t >= off) ? s[t - off] : 0;
        __syncthreads();
        s[t] += x;
        __syncthreads();
    }
    if (i < N_NODES) row_start[i] = s[t] - v;
    if (t == 255) blkSums[blockIdx.x] = s[255];
}

__global__ __launch_bounds__(512) void scan_l2(int* __restrict__ blkSums, int nblk) {
    __shared__ int s[512];
    const int t = threadIdx.x;
    int v = (t < nblk) ? blkSums[t] : 0;
    s[t] = v;
    __syncthreads();
#pragma unroll
    for (int off = 1; off < 512; off <<= 1) {
        int x = (t >= off) ? s[t - off] : 0;
        __syncthreads();
        s[t] += x;
        __syncthreads();
    }
    if (t < nblk) blkSums[t] = s[t] - v;
}

__global__ __launch_bounds__(256) void scan_l3(int* __restrict__ row_start,
                                               const int* __restrict__ blkSums) {
    const int i = blockIdx.x * 256 + threadIdx.x;
    if (i < N_NODES) row_start[i] += blkSums[blockIdx.x];
    if (i == 0) row_start[N_NODES] = N_EDGES;
}

// ---------------------------------------------------------------------------
// Contention-free bucket binning at proper occupancy (640 chunk-blocks).
// c2d is chunk-major: c2d[chunk][bucket] -> bucket_count writes and
// bucket_scatter2 reads are contiguous per block.
// ---------------------------------------------------------------------------
__global__ __launch_bounds__(256) void bucket_count(const int* __restrict__ rows,
                                                    int* __restrict__ c2d) {
    __shared__ int h[N_BUCKETS];
    for (int i = threadIdx.x; i < N_BUCKETS; i += 256) h[i] = 0;
    __syncthreads();
    const int base = blockIdx.x * EPB;
    for (int i = threadIdx.x; i < EPB; i += 256)
        atomicAdd(&h[rows[base + i] >> BUCKET_BITS], 1);
    __syncthreads();
    for (int b = threadIdx.x; b < N_BUCKETS; b += 256)
        c2d[(size_t)blockIdx.x * C2D_STRIDE + b] = h[b];
}

// Per-bucket exclusive scan over the 640 chunk-counts: one wave per bucket,
// 10 chunks per lane (640 = 64*10 exact).
__global__ __launch_bounds__(64) void scan_chunks(int* __restrict__ c2d) {
    const int b = blockIdx.x;
    const int t = threadIdx.x;
    int loc[CPL];
    int sum = 0;
#pragma unroll
    for (int j = 0; j < CPL; ++j) {
        int k = t * CPL + j;
        int v = c2d[(size_t)k * C2D_STRIDE + b];
        loc[j] = sum;
        sum += v;
    }
    int s = sum;
#pragma unroll
    for (int off = 1; off < 64; off <<= 1) {
        int u = __shfl_up(s, off);
        if (t >= off) s += u;
    }
    int base = s - sum;                  // exclusive over lanes
#pragma unroll
    for (int j = 0; j < CPL; ++j) {
        int k = t * CPL + j;
        c2d[(size_t)k * C2D_STRIDE + b] = base + loc[j];
    }
}

// Scatter edges into bucket-contiguous etmp via reserved per-(block,bucket)
// slices; LDS offset counters (no hot global atomics).
// Record: x = col(17b) | (row&31)<<17 ; y = val bits.
__global__ __launch_bounds__(256) void bucket_scatter2(const int* __restrict__ rows,
                                                       const int* __restrict__ cols,
                                                       const float* __restrict__ vals,
                                                       const int* __restrict__ c2d,
                                                       const int* __restrict__ row_start,
                                                       uint2* __restrict__ etmp) {
    __shared__ int off[N_BUCKETS];
    const int blk = blockIdx.x;
    for (int b = threadIdx.x; b < N_BUCKETS; b += 256)
        off[b] = row_start[b << BUCKET_BITS] + c2d[(size_t)blk * C2D_STRIDE + b];
    __syncthreads();
    const int base = blk * EPB;
    for (int i = threadIdx.x; i < EPB; i += 256) {
        int e = base + i;
        int r = rows[e];
        int b = r >> BUCKET_BITS;
        int pos = atomicAdd(&off[b], 1);
        etmp[pos] = make_uint2((unsigned)cols[e] |
                               ((unsigned)(r & (BUCKET_ROWS - 1)) << 17),
                               __float_as_uint(vals[e]));
    }
}

// Per-bucket row sort into the final CSR order (L2-hot 3 KB windows).
__global__ __launch_bounds__(256) void bucket_sort(const uint2* __restrict__ etmp,
                                                   const int* __restrict__ row_start,
                                                   uint2* __restrict__ edge_s) {
    __shared__ int cnt[BUCKET_ROWS];
    const int b = blockIdx.x;
    const int t = threadIdx.x;
    if (t < BUCKET_ROWS) cnt[t] = 0;
    __syncthreads();

    const int r0 = b << BUCKET_BITS;
    const int bstart = row_start[r0];
    const int bend   = row_start[r0 + BUCKET_ROWS];

    for (int e = bstart + t; e < bend; e += 256) {
        uint2 u = etmp[e];
        int lr = (int)(u.x >> 17);
        int pos = row_start[r0 + lr] + atomicAdd(&cnt[lr], 1);
        edge_s[pos] = make_uint2(u.x & 0x1FFFFu, u.y);
    }
}

// ---------------------------------------------------------------------------
// Gather: wave per row, half-wave per edge, 4 gathers in flight, register
// accumulate, out written exactly once (validated R5/R8).
// ---------------------------------------------------------------------------
__global__ __launch_bounds__(256) void spmm_gather(const uint2* __restrict__ edge_s,
                                                   const int* __restrict__ row_start,
                                                   const ushort* __restrict__ support,
                                                   float* __restrict__ out) {
    const int r = blockIdx.x * 4 + (threadIdx.x >> 6);
    if (r >= N_NODES) return;
    const int lane = threadIdx.x & 63;
    const int h = lane >> 5;        // which edge of the pair
    const int c = lane & 31;        // column pair: cols {2c, 2c+1}

    int e   = row_start[r];
    int end = row_start[r + 1];
    float2 acc = {0.f, 0.f};

    for (; e + 3 < end; e += 4) {
        uint2 p0 = edge_s[e + h];
        uint2 p1 = edge_s[e + 2 + h];
        unsigned s0 = *reinterpret_cast<const unsigned*>(support + (size_t)p0.x * D_OUT + 2 * c);
        unsigned s1 = *reinterpret_cast<const unsigned*>(support + (size_t)p1.x * D_OUT + 2 * c);
        float v0 = __uint_as_float(p0.y);
        float v1 = __uint_as_float(p1.y);
        acc.x = fmaf(v0, bf16_to_f32((ushort)(s0 & 0xFFFFu)), acc.x);
        acc.y = fmaf(v0, bf16_to_f32((ushort)(s0 >> 16)), acc.y);
        acc.x = fmaf(v1, bf16_to_f32((ushort)(s1 & 0xFFFFu)), acc.x);
        acc.y = fmaf(v1, bf16_to_f32((ushort)(s1 >> 16)), acc.y);
    }
    for (int ee = e + h; ee < end; ee += 2) {
        uint2 p = edge_s[ee];
        unsigned s = *reinterpret_cast<const unsigned*>(support + (size_t)p.x * D_OUT + 2 * c);
        float v = __uint_as_float(p.y);
        acc.x = fmaf(v, bf16_to_f32((ushort)(s & 0xFFFFu)), acc.x);
        acc.y = fmaf(v, bf16_to_f32((ushort)(s >> 16)), acc.y);
    }

    acc.x += __shfl_xor(acc.x, 32);
    acc.y += __shfl_xor(acc.y, 32);
    if (h == 0)
        *reinterpret_cast<float2*>(out + (size_t)r * D_OUT + 2 * c) = acc;
}

// ---------------------------------------------------------------------------
// Fallback path (ws too small): zero + atomic scatter from bf16 support.
// ---------------------------------------------------------------------------
__global__ void zero_out(float4* __restrict__ out, int n4) {
    int i = blockIdx.x * blockDim.x + threadIdx.x;
    int stride = gridDim.x * blockDim.x;
    for (; i < n4; i += stride) out[i] = float4{0.0f, 0.0f, 0.0f, 0.0f};
}

__global__ __launch_bounds__(256) void spmm_scatter(const int* __restrict__ rows,
                                                    const int* __restrict__ cols,
                                                    const float* __restrict__ vals,
                                                    const ushort* __restrict__ support,
                                                    float* __restrict__ out,
                                                    int n_edges) {
    const int lane = threadIdx.x & 63;
    const int wave_global = (int)((blockIdx.x * blockDim.x + threadIdx.x) >> 6);
    const int n_waves = (int)((gridDim.x * blockDim.x) >> 6);

    for (int base = wave_global * 64; base < n_edges; base += n_waves * 64) {
        int my_e = base + lane;
        int r = rows[my_e];
        int c = cols[my_e];
        float v = vals[my_e];

        int cnt = min(64, n_edges - base);
        for (int i = 0; i < cnt; ++i) {
            int row = __shfl(r, i);
            int col = __shfl(c, i);
            float val = __shfl(v, i);
            float s = bf16_to_f32(support[(size_t)col * D_OUT + lane]);
            atomicAdd(&out[(size_t)row * D_OUT + lane], val * s);
        }
    }
}

extern "C" void kernel_launch(void* const* d_in, const int* in_sizes, int n_in,
                              void* d_out, int out_size, void* d_ws, size_t ws_size,
                              hipStream_t stream) {
    const float* X      = (const float*)d_in[0];
    const float* W      = (const float*)d_in[1];
    const int*   A_rows = (const int*)d_in[2];
    const int*   A_cols = (const int*)d_in[3];
    const float* A_vals = (const float*)d_in[4];
    float* out = (float*)d_out;

    char* ws = (char*)d_ws;
    ushort* support = (ushort*)(ws + OFF_SUPPORT);

    const int gemm_blocks = (N_NODES + 127) / 128;  // 782

    if (ws_size >= (size_t)WS_NEEDED) {
        int*   row_start = (int*)(ws + OFF_ROWSTART);
        int*   counts    = (int*)(ws + OFF_COUNTS);
        int*   c2d       = (int*)(ws + OFF_C2D);     // aliases edge_s region
        uint2* etmp      = (uint2*)(ws + OFF_ETMP);
        uint2* edge_s    = (uint2*)(ws + OFF_EDGES);
        int*   blkSums   = (int*)(ws + OFF_BLKSUMS);

        const int nblk_scan = (N_NODES + 255) / 256;  // 391

        // per-row CSR offsets
        zero_ints<<<256, 256, 0, stream>>>(counts, N_NODES);
        hist_rows<<<1024, 256, 0, stream>>>(A_rows, counts);
        scan_l1<<<nblk_scan, 256, 0, stream>>>(counts, row_start, blkSums);
        scan_l2<<<1, 512, 0, stream>>>(blkSums, nblk_scan);
        scan_l3<<<nblk_scan, 256, 0, stream>>>(row_start, blkSums);

        // contention-free binning into row-sorted edge_s
        bucket_count<<<NBLK_E, 256, 0, stream>>>(A_rows, c2d);
        scan_chunks<<<N_BUCKETS, 64, 0, stream>>>(c2d);
        bucket_scatter2<<<NBLK_E, 256, 0, stream>>>(A_rows, A_cols, A_vals,
                                                    c2d, row_start, etmp);
        bucket_sort<<<N_BUCKETS, 256, 0, stream>>>(etmp, row_start, edge_s);

        // support = bf16(X @ W)  (MFMA)
        gemm_xw_mfma<<<gemm_blocks, 256, 0, stream>>>(X, W, support);

        // out = A @ support (register-accumulate gather, no atomics)
        spmm_gather<<<(N_NODES + 3) / 4, 256, 0, stream>>>(edge_s, row_start,
                                                           support, out);
    } else {
        int n4 = (N_NODES * D_OUT) / 4;
        zero_out<<<2048, 256, 0, stream>>>((float4*)out, n4);
        gemm_xw_mfma<<<gemm_blocks, 256, 0, stream>>>(X, W, support);
        int chunks = N_EDGES / 64;
        spmm_scatter<<<(chunks + 3) / 4, 256, 0, stream>>>(A_rows, A_cols, A_vals,
                                                           support, out, N_EDGES);
    }
}

// Round 11
// 186.013 us; speedup vs baseline: 1.1514x; 1.1514x over previous
//
#include <hip/hip_runtime.h>

#define N_NODES 100000
#define N_EDGES 1200000
#define D_IN 256
#define D_OUT 64

#define BUCKET_BITS 5
#define BUCKET_ROWS 32
#define N_BUCKETS   (N_NODES / BUCKET_ROWS)      // 3125 exact
#define NBLK_E      640
#define EPB         (N_EDGES / NBLK_E)           // 1875 exact
#define N_GROUPS    196                           // ceil(3125/16); 196*16=3136
#define CPL         10                            // chunks per lane (640/64)

// c2d[group][chunk][16] : one 64B line per (group,chunk). 196*640*16*4 = 8,028,160 B.
#define C2D_IDX(b, k) ((((size_t)((b) >> 4) * NBLK_E + (k)) << 4) | ((b) & 15))

// ---- workspace layout (bytes) ----------------------------------------------
// c2d ALIASES the edge_s region: fully consumed by bucket_scatter2 before
// bucket_sort writes edge_s (stream-ordered).
#define OFF_SUPPORT   0u            // bf16 support: 12,800,000
#define OFF_ROWSTART  12800000u     // (N_NODES+1)*4 -> pad 400,016
#define OFF_COUNTS    13200016u     // 400,000
#define OFF_ETMP      13600016u     // 1.2M*8 = 9,600,000
#define OFF_EDGES     23200016u     // 9,600,000  (c2d alias: 8,028,160)
#define OFF_C2D       OFF_EDGES
#define OFF_BLKSUMS   32800016u     // 2,048
#define WS_NEEDED     32802064u

using bf16x8 = __attribute__((ext_vector_type(8))) short;
using f32x4  = __attribute__((ext_vector_type(4))) float;

static __device__ __forceinline__ ushort f32_to_bf16_rne(float f) {
    unsigned bits = __float_as_uint(f);
    unsigned r = (bits + 0x7FFFu + ((bits >> 16) & 1u)) >> 16;
    return (ushort)r;
}
static __device__ __forceinline__ float bf16_to_f32(ushort u) {
    return __uint_as_float((unsigned)u << 16);
}
static __device__ __forceinline__ unsigned pack2bf(float a, float b) {
    return (unsigned)f32_to_bf16_rne(a) | ((unsigned)f32_to_bf16_rne(b) << 16);
}

// ---------------------------------------------------------------------------
// support(bf16) = X @ W — MFMA 16x16x32 bf16 (unchanged, verified R4-R9).
// ---------------------------------------------------------------------------
__global__ __launch_bounds__(256, 4) void gemm_xw_mfma(const float* __restrict__ X,
                                                       const float* __restrict__ W,
                                                       ushort* __restrict__ support) {
    __shared__ ushort XsT[4][128][8];
    __shared__ ushort WtT[32][64][8];

    const int t = threadIdx.x;
    const int row0 = blockIdx.x * 128;
    const int lane = t & 63;
    const int w = t >> 6;
    const int lr = lane & 15;
    const int lg = lane >> 4;

#pragma unroll
    for (int p = 0; p < 16; ++p) {
        int idx = t + p * 256;
        int k   = idx >> 4;
        int c4  = idx & 15;
        float4 v = *reinterpret_cast<const float4*>(W + (size_t)k * D_OUT + c4 * 4);
        WtT[k >> 3][c4 * 4 + 0][k & 7] = f32_to_bf16_rne(v.x);
        WtT[k >> 3][c4 * 4 + 1][k & 7] = f32_to_bf16_rne(v.y);
        WtT[k >> 3][c4 * 4 + 2][k & 7] = f32_to_bf16_rne(v.z);
        WtT[k >> 3][c4 * 4 + 3][k & 7] = f32_to_bf16_rne(v.w);
    }

    int  xrow[4], xq[4];
    bool xval[4];
#pragma unroll
    for (int p = 0; p < 4; ++p) {
        int idx = t + p * 256;
        xrow[p] = idx >> 3;
        xq[p]   = idx & 7;
        xval[p] = (row0 + xrow[p]) < N_NODES;
    }

    float4 xreg[4];
#pragma unroll
    for (int p = 0; p < 4; ++p) {
        xreg[p] = make_float4(0.f, 0.f, 0.f, 0.f);
        if (xval[p])
            xreg[p] = *reinterpret_cast<const float4*>(
                X + (size_t)(row0 + xrow[p]) * D_IN + xq[p] * 4);
    }

    f32x4 acc[2][4];
#pragma unroll
    for (int mi = 0; mi < 2; ++mi)
#pragma unroll
        for (int ni = 0; ni < 4; ++ni) acc[mi][ni] = (f32x4){0.f, 0.f, 0.f, 0.f};

    for (int kt = 0; kt < 8; ++kt) {
#pragma unroll
        for (int p = 0; p < 4; ++p) {
            uint2 u;
            u.x = pack2bf(xreg[p].x, xreg[p].y);
            u.y = pack2bf(xreg[p].z, xreg[p].w);
            *reinterpret_cast<uint2*>(&XsT[xq[p] >> 1][xrow[p]][(xq[p] & 1) * 4]) = u;
        }
        __syncthreads();

        if (kt < 7) {
#pragma unroll
            for (int p = 0; p < 4; ++p) {
                if (xval[p])
                    xreg[p] = *reinterpret_cast<const float4*>(
                        X + (size_t)(row0 + xrow[p]) * D_IN + (kt + 1) * 32 + xq[p] * 4);
            }
        }

        bf16x8 a0 = *reinterpret_cast<const bf16x8*>(&XsT[lg][w * 32 + lr][0]);
        bf16x8 a1 = *reinterpret_cast<const bf16x8*>(&XsT[lg][w * 32 + 16 + lr][0]);
#pragma unroll
        for (int ni = 0; ni < 4; ++ni) {
            bf16x8 b = *reinterpret_cast<const bf16x8*>(&WtT[kt * 4 + lg][ni * 16 + lr][0]);
            acc[0][ni] = __builtin_amdgcn_mfma_f32_16x16x32_bf16(a0, b, acc[0][ni], 0, 0, 0);
            acc[1][ni] = __builtin_amdgcn_mfma_f32_16x16x32_bf16(a1, b, acc[1][ni], 0, 0, 0);
        }
        __syncthreads();
    }

#pragma unroll
    for (int mi = 0; mi < 2; ++mi) {
#pragma unroll
        for (int reg = 0; reg < 4; ++reg) {
            int grow = row0 + w * 32 + mi * 16 + lg * 4 + reg;
            if (grow < N_NODES) {
#pragma unroll
                for (int ni = 0; ni < 4; ++ni)
                    support[(size_t)grow * D_OUT + ni * 16 + lr] =
                        f32_to_bf16_rne(acc[mi][ni][reg]);
            }
        }
    }
}

// ---------------------------------------------------------------------------
// CSR offsets
// ---------------------------------------------------------------------------
__global__ void zero_ints(int* __restrict__ a, int n) {
    int i = blockIdx.x * blockDim.x + threadIdx.x;
    int stride = gridDim.x * blockDim.x;
    for (; i < n; i += stride) a[i] = 0;
}

// Fused: per-chunk LDS bucket histogram (-> c2d, line-granular) AND global
// per-row counts (12 edges/counter avg -> negligible contention). One pass
// over rows instead of two.
__global__ __launch_bounds__(256) void count_fused(const int* __restrict__ rows,
                                                   int* __restrict__ c2d,
                                                   int* __restrict__ counts) {
    __shared__ int h[N_BUCKETS];
    for (int i = threadIdx.x; i < N_BUCKETS; i += 256) h[i] = 0;
    __syncthreads();
    const int base = blockIdx.x * EPB;
    for (int i = threadIdx.x; i < EPB; i += 256) {
        int r = rows[base + i];
        atomicAdd(&h[r >> BUCKET_BITS], 1);
        atomicAdd(&counts[r], 1);
    }
    __syncthreads();
    const int k = blockIdx.x;
    for (int b = threadIdx.x; b < N_GROUPS * 16; b += 256)
        c2d[C2D_IDX(b, k)] = (b < N_BUCKETS) ? h[b] : 0;
}

__global__ __launch_bounds__(256) void scan_l1(const int* __restrict__ counts,
                                               int* __restrict__ row_start,
                                               int* __restrict__ blkSums) {
    __shared__ int s[256];
    const int t = threadIdx.x;
    const int i = blockIdx.x * 256 + t;
    int v = (i < N_NODES) ? counts[i] : 0;
    s[t] = v;
    __syncthreads();
#pragma unroll
    for (int off = 1; off < 256; off <<= 1) {
        int x = (t >= off) ? s[t - off] : 0;
        __syncthreads();
        s[t] += x;
        __syncthreads();
    }
    if (i < N_NODES) row_start[i] = s[t] - v;
    if (t == 255) blkSums[blockIdx.x] = s[255];
}

__global__ __launch_bounds__(512) void scan_l2(int* __restrict__ blkSums, int nblk) {
    __shared__ int s[512];
    const int t = threadIdx.x;
    int v = (t < nblk) ? blkSums[t] : 0;
    s[t] = v;
    __syncthreads();
#pragma unroll
    for (int off = 1; off < 512; off <<= 1) {
        int x = (t >= off) ? s[t - off] : 0;
        __syncthreads();
        s[t] += x;
        __syncthreads();
    }
    if (t < nblk) blkSums[t] = s[t] - v;
}

__global__ __launch_bounds__(256) void scan_l3(int* __restrict__ row_start,
                                               const int* __restrict__ blkSums) {
    const int i = blockIdx.x * 256 + threadIdx.x;
    if (i < N_NODES) row_start[i] += blkSums[blockIdx.x];
    if (i == 0) row_start[N_NODES] = N_EDGES;
}

// ---------------------------------------------------------------------------
// Per-bucket exclusive scan over the 640 chunk counts. One block per GROUP of
// 16 buckets: contiguous 40KB load -> LDS transpose -> wave-scan (4 waves x
// 4 buckets x 640 values) -> contiguous store. All global traffic coalesced.
// ---------------------------------------------------------------------------
__global__ __launch_bounds__(256) void scan_groups(int* __restrict__ c2d) {
    __shared__ int T[16][NBLK_E + 4];    // pad 4: banks spread on both phases
    const int t = threadIdx.x;
    const int w = t >> 6;
    const int l = t & 63;
    const size_t base = (size_t)blockIdx.x * NBLK_E * 16;

    for (int i = t; i < NBLK_E * 16; i += 256) {
        int k = i >> 4, bl = i & 15;
        T[bl][k] = c2d[base + i];
    }
    __syncthreads();

#pragma unroll
    for (int q = 0; q < 4; ++q) {
        const int bl = w * 4 + q;
        int loc[CPL];
        int sum = 0;
#pragma unroll
        for (int j = 0; j < CPL; ++j) {
            int v = T[bl][l * CPL + j];
            loc[j] = sum;
            sum += v;
        }
        int s = sum;
#pragma unroll
        for (int off = 1; off < 64; off <<= 1) {
            int u = __shfl_up(s, off);
            if (l >= off) s += u;
        }
        int ex = s - sum;
#pragma unroll
        for (int j = 0; j < CPL; ++j)
            T[bl][l * CPL + j] = ex + loc[j];
    }
    __syncthreads();

    for (int i = t; i < NBLK_E * 16; i += 256) {
        int k = i >> 4, bl = i & 15;
        c2d[base + i] = T[bl][k];
    }
}

// Scatter edges into bucket-contiguous etmp via reserved per-(block,bucket)
// slices; LDS offset counters (no hot global atomics).
// Record: x = col(17b) | (row&31)<<17 ; y = val bits.
__global__ __launch_bounds__(256) void bucket_scatter2(const int* __restrict__ rows,
                                                       const int* __restrict__ cols,
                                                       const float* __restrict__ vals,
                                                       const int* __restrict__ c2d,
                                                       const int* __restrict__ row_start,
                                                       uint2* __restrict__ etmp) {
    __shared__ int off[N_BUCKETS];
    const int blk = blockIdx.x;
    for (int b = threadIdx.x; b < N_BUCKETS; b += 256)
        off[b] = row_start[b << BUCKET_BITS] + c2d[C2D_IDX(b, blk)];
    __syncthreads();
    const int base = blk * EPB;
    for (int i = threadIdx.x; i < EPB; i += 256) {
        int e = base + i;
        int r = rows[e];
        int b = r >> BUCKET_BITS;
        int pos = atomicAdd(&off[b], 1);
        etmp[pos] = make_uint2((unsigned)cols[e] |
                               ((unsigned)(r & (BUCKET_ROWS - 1)) << 17),
                               __float_as_uint(vals[e]));
    }
}

// Per-bucket row sort into final CSR order (L2-hot 3KB windows).
__global__ __launch_bounds__(256) void bucket_sort(const uint2* __restrict__ etmp,
                                                   const int* __restrict__ row_start,
                                                   uint2* __restrict__ edge_s) {
    __shared__ int cnt[BUCKET_ROWS];
    const int b = blockIdx.x;
    const int t = threadIdx.x;
    if (t < BUCKET_ROWS) cnt[t] = 0;
    __syncthreads();

    const int r0 = b << BUCKET_BITS;
    const int bstart = row_start[r0];
    const int bend   = row_start[r0 + BUCKET_ROWS];

    for (int e = bstart + t; e < bend; e += 256) {
        uint2 u = etmp[e];
        int lr = (int)(u.x >> 17);
        int pos = row_start[r0 + lr] + atomicAdd(&cnt[lr], 1);
        edge_s[pos] = make_uint2(u.x & 0x1FFFFu, u.y);
    }
}

// ---------------------------------------------------------------------------
// Gather: wave per row, half-wave per edge, 4 gathers in flight, register
// accumulate, out written exactly once (validated R5/R8/R9).
// ---------------------------------------------------------------------------
__global__ __launch_bounds__(256) void spmm_gather(const uint2* __restrict__ edge_s,
                                                   const int* __restrict__ row_start,
                                                   const ushort* __restrict__ support,
                                                   float* __restrict__ out) {
    const int r = blockIdx.x * 4 + (threadIdx.x >> 6);
    if (r >= N_NODES) return;
    const int lane = threadIdx.x & 63;
    const int h = lane >> 5;        // which edge of the pair
    const int c = lane & 31;        // column pair: cols {2c, 2c+1}

    int e   = row_start[r];
    int end = row_start[r + 1];
    float2 acc = {0.f, 0.f};

    for (; e + 3 < end; e += 4) {
        uint2 p0 = edge_s[e + h];
        uint2 p1 = edge_s[e + 2 + h];
        unsigned s0 = *reinterpret_cast<const unsigned*>(support + (size_t)p0.x * D_OUT + 2 * c);
        unsigned s1 = *reinterpret_cast<const unsigned*>(support + (size_t)p1.x * D_OUT + 2 * c);
        float v0 = __uint_as_float(p0.y);
        float v1 = __uint_as_float(p1.y);
        acc.x = fmaf(v0, bf16_to_f32((ushort)(s0 & 0xFFFFu)), acc.x);
        acc.y = fmaf(v0, bf16_to_f32((ushort)(s0 >> 16)), acc.y);
        acc.x = fmaf(v1, bf16_to_f32((ushort)(s1 & 0xFFFFu)), acc.x);
        acc.y = fmaf(v1, bf16_to_f32((ushort)(s1 >> 16)), acc.y);
    }
    for (int ee = e + h; ee < end; ee += 2) {
        uint2 p = edge_s[ee];
        unsigned s = *reinterpret_cast<const unsigned*>(support + (size_t)p.x * D_OUT + 2 * c);
        float v = __uint_as_float(p.y);
        acc.x = fmaf(v, bf16_to_f32((ushort)(s & 0xFFFFu)), acc.x);
        acc.y = fmaf(v, bf16_to_f32((ushort)(s >> 16)), acc.y);
    }

    acc.x += __shfl_xor(acc.x, 32);
    acc.y += __shfl_xor(acc.y, 32);
    if (h == 0)
        *reinterpret_cast<float2*>(out + (size_t)r * D_OUT + 2 * c) = acc;
}

// ---------------------------------------------------------------------------
// Fallback path (ws too small): zero + atomic scatter from bf16 support.
// ---------------------------------------------------------------------------
__global__ void zero_out(float4* __restrict__ out, int n4) {
    int i = blockIdx.x * blockDim.x + threadIdx.x;
    int stride = gridDim.x * blockDim.x;
    for (; i < n4; i += stride) out[i] = float4{0.0f, 0.0f, 0.0f, 0.0f};
}

__global__ __launch_bounds__(256) void spmm_scatter(const int* __restrict__ rows,
                                                    const int* __restrict__ cols,
                                                    const float* __restrict__ vals,
                                                    const ushort* __restrict__ support,
                                                    float* __restrict__ out,
                                                    int n_edges) {
    const int lane = threadIdx.x & 63;
    const int wave_global = (int)((blockIdx.x * blockDim.x + threadIdx.x) >> 6);
    const int n_waves = (int)((gridDim.x * blockDim.x) >> 6);

    for (int base = wave_global * 64; base < n_edges; base += n_waves * 64) {
        int my_e = base + lane;
        int r = rows[my_e];
        int c = cols[my_e];
        float v = vals[my_e];

        int cnt = min(64, n_edges - base);
        for (int i = 0; i < cnt; ++i) {
            int row = __shfl(r, i);
            int col = __shfl(c, i);
            float val = __shfl(v, i);
            float s = bf16_to_f32(support[(size_t)col * D_OUT + lane]);
            atomicAdd(&out[(size_t)row * D_OUT + lane], val * s);
        }
    }
}

extern "C" void kernel_launch(void* const* d_in, const int* in_sizes, int n_in,
                              void* d_out, int out_size, void* d_ws, size_t ws_size,
                              hipStream_t stream) {
    const float* X      = (const float*)d_in[0];
    const float* W      = (const float*)d_in[1];
    const int*   A_rows = (const int*)d_in[2];
    const int*   A_cols = (const int*)d_in[3];
    const float* A_vals = (const float*)d_in[4];
    float* out = (float*)d_out;

    char* ws = (char*)d_ws;
    ushort* support = (ushort*)(ws + OFF_SUPPORT);

    const int gemm_blocks = (N_NODES + 127) / 128;  // 782

    if (ws_size >= (size_t)WS_NEEDED) {
        int*   row_start = (int*)(ws + OFF_ROWSTART);
        int*   counts    = (int*)(ws + OFF_COUNTS);
        int*   c2d       = (int*)(ws + OFF_C2D);     // aliases edge_s region
        uint2* etmp      = (uint2*)(ws + OFF_ETMP);
        uint2* edge_s    = (uint2*)(ws + OFF_EDGES);
        int*   blkSums   = (int*)(ws + OFF_BLKSUMS);

        const int nblk_scan = (N_NODES + 255) / 256;  // 391

        // per-row counts + per-chunk bucket hist (fused single pass)
        zero_ints<<<256, 256, 0, stream>>>(counts, N_NODES);
        count_fused<<<NBLK_E, 256, 0, stream>>>(A_rows, c2d, counts);

        // per-row CSR offsets
        scan_l1<<<nblk_scan, 256, 0, stream>>>(counts, row_start, blkSums);
        scan_l2<<<1, 512, 0, stream>>>(blkSums, nblk_scan);
        scan_l3<<<nblk_scan, 256, 0, stream>>>(row_start, blkSums);

        // per-bucket chunk-offset scan (coalesced group layout)
        scan_groups<<<N_GROUPS, 256, 0, stream>>>(c2d);

        // binning into row-sorted edge_s
        bucket_scatter2<<<NBLK_E, 256, 0, stream>>>(A_rows, A_cols, A_vals,
                                                    c2d, row_start, etmp);
        bucket_sort<<<N_BUCKETS, 256, 0, stream>>>(etmp, row_start, edge_s);

        // support = bf16(X @ W)  (MFMA)
        gemm_xw_mfma<<<gemm_blocks, 256, 0, stream>>>(X, W, support);

        // out = A @ support (register-accumulate gather, no atomics)
        spmm_gather<<<(N_NODES + 3) / 4, 256, 0, stream>>>(edge_s, row_start,
                                                           support, out);
    } else {
        int n4 = (N_NODES * D_OUT) / 4;
        zero_out<<<2048, 256, 0, stream>>>((float4*)out, n4);
        gemm_xw_mfma<<<gemm_blocks, 256, 0, stream>>>(X, W, support);
        int chunks = N_EDGES / 64;
        spmm_scatter<<<(chunks + 3) / 4, 256, 0, stream>>>(A_rows, A_cols, A_vals,
                                                           support, out, N_EDGES);
    }
}

// Round 12
// 103.645 us; speedup vs baseline: 2.0664x; 1.7947x over previous
//
#include <hip/hip_runtime.h>

#define N_NODES 100000
#define N_EDGES 1200000
#define D_IN 256
#define D_OUT 64

#define BUCKET_BITS 5
#define BUCKET_ROWS 32
#define N_BUCKETS   (N_NODES / BUCKET_ROWS)      // 3125 exact
#define NBLK_E      640
#define EPB         (N_EDGES / NBLK_E)           // 1875 exact
#define N_GROUPS    196                           // ceil(3125/16)
#define CPL         10                            // chunks per lane (640/64)
#define CAP         1536                          // LDS edge staging per bucket

// c2d[group][chunk][16] : one 64B line per (group,chunk). 196*640*16*4 = 8,028,160 B.
#define C2D_IDX(b, k) ((((size_t)((b) >> 4) * NBLK_E + (k)) << 4) | ((b) & 15))

// ---- workspace layout (bytes) ----------------------------------------------
// c2d ALIASES the edge_g region: c2d is consumed by bucket_scatter2 before
// sort_gather (fallback only) writes edge_g. Stream-ordered -> safe.
#define OFF_SUPPORT   0u            // bf16 support: 12,800,000
#define OFF_BSUM      12800000u     // 3136*4 = 12,544
#define OFF_BBASE     12812544u     // 12,544
#define OFF_ETMP      12825088u     // 1.2M*8 = 9,600,000
#define OFF_EDGEG     22425088u     // 9,600,000 (c2d alias: 8,028,160)
#define OFF_C2D       OFF_EDGEG
#define WS_NEEDED     32025088u

using bf16x8 = __attribute__((ext_vector_type(8))) short;
using f32x4  = __attribute__((ext_vector_type(4))) float;

static __device__ __forceinline__ ushort f32_to_bf16_rne(float f) {
    unsigned bits = __float_as_uint(f);
    unsigned r = (bits + 0x7FFFu + ((bits >> 16) & 1u)) >> 16;
    return (ushort)r;
}
static __device__ __forceinline__ float bf16_to_f32(ushort u) {
    return __uint_as_float((unsigned)u << 16);
}
static __device__ __forceinline__ unsigned pack2bf(float a, float b) {
    return (unsigned)f32_to_bf16_rne(a) | ((unsigned)f32_to_bf16_rne(b) << 16);
}

// ---------------------------------------------------------------------------
// support(bf16) = X @ W — MFMA 16x16x32 bf16 (unchanged, verified R4-R10).
// ---------------------------------------------------------------------------
__global__ __launch_bounds__(256, 4) void gemm_xw_mfma(const float* __restrict__ X,
                                                       const float* __restrict__ W,
                                                       ushort* __restrict__ support) {
    __shared__ ushort XsT[4][128][8];
    __shared__ ushort WtT[32][64][8];

    const int t = threadIdx.x;
    const int row0 = blockIdx.x * 128;
    const int lane = t & 63;
    const int w = t >> 6;
    const int lr = lane & 15;
    const int lg = lane >> 4;

#pragma unroll
    for (int p = 0; p < 16; ++p) {
        int idx = t + p * 256;
        int k   = idx >> 4;
        int c4  = idx & 15;
        float4 v = *reinterpret_cast<const float4*>(W + (size_t)k * D_OUT + c4 * 4);
        WtT[k >> 3][c4 * 4 + 0][k & 7] = f32_to_bf16_rne(v.x);
        WtT[k >> 3][c4 * 4 + 1][k & 7] = f32_to_bf16_rne(v.y);
        WtT[k >> 3][c4 * 4 + 2][k & 7] = f32_to_bf16_rne(v.z);
        WtT[k >> 3][c4 * 4 + 3][k & 7] = f32_to_bf16_rne(v.w);
    }

    int  xrow[4], xq[4];
    bool xval[4];
#pragma unroll
    for (int p = 0; p < 4; ++p) {
        int idx = t + p * 256;
        xrow[p] = idx >> 3;
        xq[p]   = idx & 7;
        xval[p] = (row0 + xrow[p]) < N_NODES;
    }

    float4 xreg[4];
#pragma unroll
    for (int p = 0; p < 4; ++p) {
        xreg[p] = make_float4(0.f, 0.f, 0.f, 0.f);
        if (xval[p])
            xreg[p] = *reinterpret_cast<const float4*>(
                X + (size_t)(row0 + xrow[p]) * D_IN + xq[p] * 4);
    }

    f32x4 acc[2][4];
#pragma unroll
    for (int mi = 0; mi < 2; ++mi)
#pragma unroll
        for (int ni = 0; ni < 4; ++ni) acc[mi][ni] = (f32x4){0.f, 0.f, 0.f, 0.f};

    for (int kt = 0; kt < 8; ++kt) {
#pragma unroll
        for (int p = 0; p < 4; ++p) {
            uint2 u;
            u.x = pack2bf(xreg[p].x, xreg[p].y);
            u.y = pack2bf(xreg[p].z, xreg[p].w);
            *reinterpret_cast<uint2*>(&XsT[xq[p] >> 1][xrow[p]][(xq[p] & 1) * 4]) = u;
        }
        __syncthreads();

        if (kt < 7) {
#pragma unroll
            for (int p = 0; p < 4; ++p) {
                if (xval[p])
                    xreg[p] = *reinterpret_cast<const float4*>(
                        X + (size_t)(row0 + xrow[p]) * D_IN + (kt + 1) * 32 + xq[p] * 4);
            }
        }

        bf16x8 a0 = *reinterpret_cast<const bf16x8*>(&XsT[lg][w * 32 + lr][0]);
        bf16x8 a1 = *reinterpret_cast<const bf16x8*>(&XsT[lg][w * 32 + 16 + lr][0]);
#pragma unroll
        for (int ni = 0; ni < 4; ++ni) {
            bf16x8 b = *reinterpret_cast<const bf16x8*>(&WtT[kt * 4 + lg][ni * 16 + lr][0]);
            acc[0][ni] = __builtin_amdgcn_mfma_f32_16x16x32_bf16(a0, b, acc[0][ni], 0, 0, 0);
            acc[1][ni] = __builtin_amdgcn_mfma_f32_16x16x32_bf16(a1, b, acc[1][ni], 0, 0, 0);
        }
        __syncthreads();
    }

#pragma unroll
    for (int mi = 0; mi < 2; ++mi) {
#pragma unroll
        for (int reg = 0; reg < 4; ++reg) {
            int grow = row0 + w * 32 + mi * 16 + lg * 4 + reg;
            if (grow < N_NODES) {
#pragma unroll
                for (int ni = 0; ni < 4; ++ni)
                    support[(size_t)grow * D_OUT + ni * 16 + lr] =
                        f32_to_bf16_rne(acc[mi][ni][reg]);
            }
        }
    }
}

// ---------------------------------------------------------------------------
// Per-chunk bucket histogram (LDS-private) -> line-granular c2d.
// ---------------------------------------------------------------------------
__global__ __launch_bounds__(256) void bucket_count(const int* __restrict__ rows,
                                                    int* __restrict__ c2d) {
    __shared__ int h[N_BUCKETS];
    for (int i = threadIdx.x; i < N_BUCKETS; i += 256) h[i] = 0;
    __syncthreads();
    const int base = blockIdx.x * EPB;
    for (int i = threadIdx.x; i < EPB; i += 256)
        atomicAdd(&h[rows[base + i] >> BUCKET_BITS], 1);
    __syncthreads();
    const int k = blockIdx.x;
    for (int b = threadIdx.x; b < N_GROUPS * 16; b += 256)
        c2d[C2D_IDX(b, k)] = (b < N_BUCKETS) ? h[b] : 0;
}

// ---------------------------------------------------------------------------
// Per-bucket exclusive scan over 640 chunk counts (grouped/coalesced layout);
// also emits per-bucket totals bsum[b].
// ---------------------------------------------------------------------------
__global__ __launch_bounds__(256) void scan_groups(int* __restrict__ c2d,
                                                   int* __restrict__ bsum) {
    __shared__ int T[16][NBLK_E + 4];
    const int t = threadIdx.x;
    const int w = t >> 6;
    const int l = t & 63;
    const size_t base = (size_t)blockIdx.x * NBLK_E * 16;

    for (int i = t; i < NBLK_E * 16; i += 256) {
        int k = i >> 4, bl = i & 15;
        T[bl][k] = c2d[base + i];
    }
    __syncthreads();

#pragma unroll
    for (int q = 0; q < 4; ++q) {
        const int bl = w * 4 + q;
        int loc[CPL];
        int sum = 0;
#pragma unroll
        for (int j = 0; j < CPL; ++j) {
            int v = T[bl][l * CPL + j];
            loc[j] = sum;
            sum += v;
        }
        int s = sum;
#pragma unroll
        for (int off = 1; off < 64; off <<= 1) {
            int u = __shfl_up(s, off);
            if (l >= off) s += u;
        }
        if (l == 63) bsum[blockIdx.x * 16 + bl] = s;   // bucket total
        int ex = s - sum;
#pragma unroll
        for (int j = 0; j < CPL; ++j)
            T[bl][l * CPL + j] = ex + loc[j];
    }
    __syncthreads();

    for (int i = t; i < NBLK_E * 16; i += 256) {
        int k = i >> 4, bl = i & 15;
        c2d[base + i] = T[bl][k];
    }
}

// ---------------------------------------------------------------------------
// Exclusive scan of the 3125 bucket totals (single block, R6-validated).
// ---------------------------------------------------------------------------
__global__ __launch_bounds__(256) void scan_buckets(const int* __restrict__ bsum,
                                                    int* __restrict__ bbase) {
    __shared__ int s[256];
    const int t = threadIdx.x;
    int loc[13];
    int sum = 0;
#pragma unroll
    for (int j = 0; j < 13; ++j) {
        int idx = t * 13 + j;
        int v = (idx < N_BUCKETS) ? bsum[idx] : 0;
        loc[j] = sum;
        sum += v;
    }
    s[t] = sum;
    __syncthreads();
#pragma unroll
    for (int off = 1; off < 256; off <<= 1) {
        int x = (t >= off) ? s[t - off] : 0;
        __syncthreads();
        s[t] += x;
        __syncthreads();
    }
    int base = s[t] - sum;
#pragma unroll
    for (int j = 0; j < 13; ++j) {
        int idx = t * 13 + j;
        if (idx < N_BUCKETS) bbase[idx] = base + loc[j];
    }
}

// ---------------------------------------------------------------------------
// Scatter edges into bucket-contiguous etmp via reserved per-(block,bucket)
// slices (LDS offset counters, no hot global atomics).
// Record: x = col(17b) | (row&31)<<17 ; y = val bits.
// ---------------------------------------------------------------------------
__global__ __launch_bounds__(256) void bucket_scatter2(const int* __restrict__ rows,
                                                       const int* __restrict__ cols,
                                                       const float* __restrict__ vals,
                                                       const int* __restrict__ c2d,
                                                       const int* __restrict__ bbase,
                                                       uint2* __restrict__ etmp) {
    __shared__ int off[N_BUCKETS];
    const int blk = blockIdx.x;
    for (int b = threadIdx.x; b < N_BUCKETS; b += 256)
        off[b] = bbase[b] + c2d[C2D_IDX(b, blk)];
    __syncthreads();
    const int base = blk * EPB;
    for (int i = threadIdx.x; i < EPB; i += 256) {
        int e = base + i;
        int r = rows[e];
        int b = r >> BUCKET_BITS;
        int pos = atomicAdd(&off[b], 1);
        etmp[pos] = make_uint2((unsigned)cols[e] |
                               ((unsigned)(r & (BUCKET_ROWS - 1)) << 17),
                               __float_as_uint(vals[e]));
    }
}

// ---------------------------------------------------------------------------
// Fused sort+gather: one block per bucket.
//   pass1: count the bucket's 32 rows (LDS)
//   scan:  32-wide wave scan -> local row offsets
//   pass2: place sorted (col,val) records into LDS (global fallback if >CAP)
//   gather: wave per row (8 rows/wave), half-wave edge pairs, register acc,
//           out written exactly once. No atomics near the support loads.
// ---------------------------------------------------------------------------
__global__ __launch_bounds__(256) void sort_gather(const uint2* __restrict__ etmp,
                                                   const int* __restrict__ bbase,
                                                   const int* __restrict__ bsum,
                                                   const ushort* __restrict__ support,
                                                   uint2* __restrict__ edge_g,
                                                   float* __restrict__ out) {
    __shared__ uint2 eL[CAP];                // 12,288 B
    __shared__ int cnt[BUCKET_ROWS], pos[BUCKET_ROWS], fill[BUCKET_ROWS];
    const int t = threadIdx.x;
    const int lane = t & 63;
    const int w = t >> 6;
    const int b = blockIdx.x;
    const int r0 = b << BUCKET_BITS;
    const int s0 = bbase[b];
    const int n  = bsum[b];

    if (t < BUCKET_ROWS) cnt[t] = 0;
    __syncthreads();

    // pass 1: per-row counts
    for (int i = t; i < n; i += 256)
        atomicAdd(&cnt[etmp[s0 + i].x >> 17], 1);
    __syncthreads();

    // 32-wide exclusive scan (wave 0)
    if (t < 64) {
        int v = (t < 32) ? cnt[t] : 0;
        int s = v;
#pragma unroll
        for (int off = 1; off < 32; off <<= 1) {
            int u = __shfl_up(s, off);
            if (lane >= off) s += u;
        }
        if (t < 32) { pos[t] = s - v; fill[t] = 0; }
    }
    __syncthreads();

    // pass 2: place sorted records
    const bool inLDS = (n <= CAP);
    if (inLDS) {
        for (int i = t; i < n; i += 256) {
            uint2 u = etmp[s0 + i];
            int r = (int)(u.x >> 17);
            int p = pos[r] + atomicAdd(&fill[r], 1);
            eL[p] = make_uint2(u.x & 0x1FFFFu, u.y);
        }
    } else {
        for (int i = t; i < n; i += 256) {
            uint2 u = etmp[s0 + i];
            int r = (int)(u.x >> 17);
            int p = pos[r] + atomicAdd(&fill[r], 1);
            edge_g[s0 + p] = make_uint2(u.x & 0x1FFFFu, u.y);
        }
    }
    __syncthreads();

    // gather
    const int h = lane >> 5;
    const int c = lane & 31;

#define GATHER_BODY(SRC)                                                          \
    for (int rr = w; rr < BUCKET_ROWS; rr += 4) {                                 \
        int e = pos[rr], end = pos[rr] + cnt[rr];                                 \
        float2 acc = {0.f, 0.f};                                                  \
        for (; e + 3 < end; e += 4) {                                             \
            uint2 p0 = SRC(e + h);                                                \
            uint2 p1 = SRC(e + 2 + h);                                            \
            unsigned s0v = *reinterpret_cast<const unsigned*>(                    \
                support + (size_t)p0.x * D_OUT + 2 * c);                          \
            unsigned s1v = *reinterpret_cast<const unsigned*>(                    \
                support + (size_t)p1.x * D_OUT + 2 * c);                          \
            float v0 = __uint_as_float(p0.y);                                     \
            float v1 = __uint_as_float(p1.y);                                     \
            acc.x = fmaf(v0, bf16_to_f32((ushort)(s0v & 0xFFFFu)), acc.x);        \
            acc.y = fmaf(v0, bf16_to_f32((ushort)(s0v >> 16)), acc.y);            \
            acc.x = fmaf(v1, bf16_to_f32((ushort)(s1v & 0xFFFFu)), acc.x);        \
            acc.y = fmaf(v1, bf16_to_f32((ushort)(s1v >> 16)), acc.y);            \
        }                                                                         \
        for (int ee = e + h; ee < end; ee += 2) {                                 \
            uint2 p = SRC(ee);                                                    \
            unsigned sv = *reinterpret_cast<const unsigned*>(                     \
                support + (size_t)p.x * D_OUT + 2 * c);                           \
            float v = __uint_as_float(p.y);                                       \
            acc.x = fmaf(v, bf16_to_f32((ushort)(sv & 0xFFFFu)), acc.x);          \
            acc.y = fmaf(v, bf16_to_f32((ushort)(sv >> 16)), acc.y);              \
        }                                                                         \
        acc.x += __shfl_xor(acc.x, 32);                                           \
        acc.y += __shfl_xor(acc.y, 32);                                           \
        if (h == 0)                                                               \
            *reinterpret_cast<float2*>(out + (size_t)(r0 + rr) * D_OUT + 2 * c) = acc; \
    }

    if (inLDS) {
#define SRCL(i) eL[i]
        GATHER_BODY(SRCL)
#undef SRCL
    } else {
        const uint2* eg = edge_g + s0;
#define SRCG(i) eg[i]
        GATHER_BODY(SRCG)
#undef SRCG
    }
#undef GATHER_BODY
}

// ---------------------------------------------------------------------------
// Fallback path (ws too small): zero + atomic scatter from bf16 support.
// ---------------------------------------------------------------------------
__global__ void zero_out(float4* __restrict__ out, int n4) {
    int i = blockIdx.x * blockDim.x + threadIdx.x;
    int stride = gridDim.x * blockDim.x;
    for (; i < n4; i += stride) out[i] = float4{0.0f, 0.0f, 0.0f, 0.0f};
}

__global__ __launch_bounds__(256) void spmm_scatter(const int* __restrict__ rows,
                                                    const int* __restrict__ cols,
                                                    const float* __restrict__ vals,
                                                    const ushort* __restrict__ support,
                                                    float* __restrict__ out,
                                                    int n_edges) {
    const int lane = threadIdx.x & 63;
    const int wave_global = (int)((blockIdx.x * blockDim.x + threadIdx.x) >> 6);
    const int n_waves = (int)((gridDim.x * blockDim.x) >> 6);

    for (int base = wave_global * 64; base < n_edges; base += n_waves * 64) {
        int my_e = base + lane;
        int r = rows[my_e];
        int c = cols[my_e];
        float v = vals[my_e];

        int cnt = min(64, n_edges - base);
        for (int i = 0; i < cnt; ++i) {
            int row = __shfl(r, i);
            int col = __shfl(c, i);
            float val = __shfl(v, i);
            float s = bf16_to_f32(support[(size_t)col * D_OUT + lane]);
            atomicAdd(&out[(size_t)row * D_OUT + lane], val * s);
        }
    }
}

extern "C" void kernel_launch(void* const* d_in, const int* in_sizes, int n_in,
                              void* d_out, int out_size, void* d_ws, size_t ws_size,
                              hipStream_t stream) {
    const float* X      = (const float*)d_in[0];
    const float* W      = (const float*)d_in[1];
    const int*   A_rows = (const int*)d_in[2];
    const int*   A_cols = (const int*)d_in[3];
    const float* A_vals = (const float*)d_in[4];
    float* out = (float*)d_out;

    char* ws = (char*)d_ws;
    ushort* support = (ushort*)(ws + OFF_SUPPORT);

    const int gemm_blocks = (N_NODES + 127) / 128;  // 782

    if (ws_size >= (size_t)WS_NEEDED) {
        int*   bsum   = (int*)(ws + OFF_BSUM);
        int*   bbase  = (int*)(ws + OFF_BBASE);
        int*   c2d    = (int*)(ws + OFF_C2D);     // aliases edge_g region
        uint2* etmp   = (uint2*)(ws + OFF_ETMP);
        uint2* edge_g = (uint2*)(ws + OFF_EDGEG);

        // binning offsets (contention-free)
        bucket_count<<<NBLK_E, 256, 0, stream>>>(A_rows, c2d);
        scan_groups<<<N_GROUPS, 256, 0, stream>>>(c2d, bsum);
        scan_buckets<<<1, 256, 0, stream>>>(bsum, bbase);

        // edges -> bucket-contiguous etmp
        bucket_scatter2<<<NBLK_E, 256, 0, stream>>>(A_rows, A_cols, A_vals,
                                                    c2d, bbase, etmp);

        // support = bf16(X @ W)  (MFMA)
        gemm_xw_mfma<<<gemm_blocks, 256, 0, stream>>>(X, W, support);

        // fused per-bucket row-sort + gather (register accumulate, no atomics)
        sort_gather<<<N_BUCKETS, 256, 0, stream>>>(etmp, bbase, bsum,
                                                   support, edge_g, out);
    } else {
        int n4 = (N_NODES * D_OUT) / 4;
        zero_out<<<2048, 256, 0, stream>>>((float4*)out, n4);
        gemm_xw_mfma<<<gemm_blocks, 256, 0, stream>>>(X, W, support);
        int chunks = N_EDGES / 64;
        spmm_scatter<<<(chunks + 3) / 4, 256, 0, stream>>>(A_rows, A_cols, A_vals,
                                                           support, out, N_EDGES);
    }
}